// Round 1
// baseline (3501.300 us; speedup 1.0000x reference)
//
#include <hip/hip_runtime.h>
#include <hip/hip_cooperative_groups.h>

namespace cg = cooperative_groups;

#define ALPHA 0.005f
#define SCALE 0.001f
#define DELTA 0.1f
#define MAXIT 51   // MAX_ITER + 1 scan steps

constexpr int N = 512;
constexpr int M = 512;
constexpr int NTHREADS = 1024;
constexpr int NWAVES = NTHREADS / 64;  // 16
constexpr int MPW = M / NWAVES;        // 32 constraint rows per wave
constexpr int NROWS = 256;             // B*S

// One block per (b,s) row. x lives in registers (replicated per wave),
// A is streamed once per iteration computing viol and g in one pass.
// Global early-stop via per-iteration flag in workspace + grid.sync().
__global__ __launch_bounds__(NTHREADS, 4)
void lva_kernel(const float* __restrict__ x_in,
                const float* __restrict__ A,
                const float* __restrict__ bvec,
                float* __restrict__ x_out,
                int* __restrict__ flags)
{
    __shared__ float b_lds[M];
    __shared__ float g_lds[NWAVES * N];   // 32 KiB partial-g, row 0 reused for final
    __shared__ float sv_lds[NWAVES];
    __shared__ int bc_active;
    __shared__ int bc_flag;

    const int tid  = threadIdx.x;
    const int lane = tid & 63;
    const int w    = tid >> 6;
    const int r    = blockIdx.x;          // row index 0..255

    cg::grid_group grid = cg::this_grid();

    // zero per-iteration flags (ws is poisoned 0xAA before every launch)
    if (r == 0 && tid < 64)
        __hip_atomic_store(&flags[tid], 0, __ATOMIC_RELAXED, __HIP_MEMORY_SCOPE_AGENT);

    if (tid < M) b_lds[tid] = bvec[(size_t)r * M + tid];

    // lane's 8 n-indices: [4*lane .. 4*lane+3] and [256+4*lane .. 256+4*lane+3]
    const int n0 = lane * 4;
    const int n1 = 256 + lane * 4;

    const float* xrow = x_in + (size_t)r * N;
    float4 xa = *(const float4*)(xrow + n0);
    float4 xb = *(const float4*)(xrow + n1);

    const float* Ablk = A + (size_t)r * M * N;

    grid.sync();   // flags zeroed + b_lds visible

    bool my_active = true;

    for (int t = 0; t < MAXIT; ++t) {
        bool new_active = false;
        if (my_active) {   // block-uniform
            float4 ga = make_float4(0.f, 0.f, 0.f, 0.f);
            float4 gb = make_float4(0.f, 0.f, 0.f, 0.f);
            float sviol = 0.f;
            for (int k = 0; k < MPW; ++k) {
                const int m = w + NWAVES * k;          // wave-uniform, strided
                const float* ar = Ablk + (size_t)m * N;
                float4 aa = *(const float4*)(ar + n0); // coalesced 1KB/wave
                float4 ab = *(const float4*)(ar + n1);
                float d = aa.x*xa.x + aa.y*xa.y + aa.z*xa.z + aa.w*xa.w
                        + ab.x*xb.x + ab.y*xb.y + ab.z*xb.z + ab.w*xb.w;
                #pragma unroll
                for (int off = 32; off > 0; off >>= 1)
                    d += __shfl_xor(d, off, 64);       // all lanes hold full dot
                float viol = d - b_lds[m];
                viol = viol > 0.f ? viol : 0.f;
                sviol += viol;
                // reuse A regs: g += viol * A[m,:]
                ga.x += viol*aa.x; ga.y += viol*aa.y; ga.z += viol*aa.z; ga.w += viol*aa.w;
                gb.x += viol*ab.x; gb.y += viol*ab.y; gb.z += viol*ab.z; gb.w += viol*ab.w;
            }
            if (lane == 0) sv_lds[w] = sviol;
            *(float4*)(&g_lds[w * N + n0]) = ga;
            *(float4*)(&g_lds[w * N + n1]) = gb;
            __syncthreads();
            if (tid == 0) {
                float s = 0.f;
                #pragma unroll
                for (int i = 0; i < NWAVES; ++i) s += sv_lds[i];
                int na = (s >= DELTA) ? 1 : 0;
                bc_active = na;
                if (na) atomicOr(&flags[t], 1);        // device-scope
            }
            if (tid < N) {                             // cross-wave g reduce (column tid)
                float s = 0.f;
                #pragma unroll
                for (int i = 0; i < NWAVES; ++i) s += g_lds[i * N + tid];
                g_lds[tid] = s;                        // only this thread touches col tid
            }
            __syncthreads();
            new_active = (bc_active != 0);
            if (new_active) {
                // stop_early implies no row has new_active, so updating here is
                // always consistent with the reference's where(stop_early, x, x_upd)
                float4 gfa = *(const float4*)(&g_lds[n0]);
                float4 gfb = *(const float4*)(&g_lds[n1]);
                xa.x = fmaxf(xa.x - (ALPHA / (1.f + SCALE*gfa.x)) * gfa.x, 0.f);
                xa.y = fmaxf(xa.y - (ALPHA / (1.f + SCALE*gfa.y)) * gfa.y, 0.f);
                xa.z = fmaxf(xa.z - (ALPHA / (1.f + SCALE*gfa.z)) * gfa.z, 0.f);
                xa.w = fmaxf(xa.w - (ALPHA / (1.f + SCALE*gfa.w)) * gfa.w, 0.f);
                xb.x = fmaxf(xb.x - (ALPHA / (1.f + SCALE*gfb.x)) * gfb.x, 0.f);
                xb.y = fmaxf(xb.y - (ALPHA / (1.f + SCALE*gfb.y)) * gfb.y, 0.f);
                xb.z = fmaxf(xb.z - (ALPHA / (1.f + SCALE*gfb.z)) * gfb.z, 0.f);
                xb.w = fmaxf(xb.w - (ALPHA / (1.f + SCALE*gfb.w)) * gfb.w, 0.f);
            }
        }
        grid.sync();   // all flag[t] writes visible before reads
        if (tid == 0)
            bc_flag = __hip_atomic_load(&flags[t], __ATOMIC_RELAXED, __HIP_MEMORY_SCOPE_AGENT);
        __syncthreads();
        if (bc_flag == 0) break;   // global early stop — uniform across all blocks
        my_active = new_active;    // inactive rows never reactivate (x unchanged)
    }

    float* orow = x_out + (size_t)r * N;
    if (w == 0) {   // x replicated & identical across waves; wave 0 writes
        *(float4*)(orow + n0) = xa;
        *(float4*)(orow + n1) = xb;
    }
}

extern "C" void kernel_launch(void* const* d_in, const int* in_sizes, int n_in,
                              void* d_out, int out_size, void* d_ws, size_t ws_size,
                              hipStream_t stream)
{
    const float* x  = (const float*)d_in[0];
    const float* A  = (const float*)d_in[1];
    const float* b  = (const float*)d_in[2];
    float* out      = (float*)d_out;
    int* flags      = (int*)d_ws;

    void* args[] = { (void*)&x, (void*)&A, (void*)&b, (void*)&out, (void*)&flags };
    hipLaunchCooperativeKernel((const void*)lva_kernel,
                               dim3(NROWS), dim3(NTHREADS),
                               args, 0, stream);
}